// Round 1
// baseline (253.732 us; speedup 1.0000x reference)
//
#include <hip/hip_runtime.h>

#define SB 32      // batch
#define SS 2048    // sequence
#define SH 2       // heads
#define SD 4       // head dim
#define SE 8       // embed

// ---------------------------------------------------------------------------
// Kernel 1: moving averages (8 odd kernel sizes, replicate pad == clamped
// symmetric window) + QKV projection (4x4 per head, scale 1/sqrt(D) folded
// into q). One block = 256 consecutive positions of one batch row.
// ---------------------------------------------------------------------------
__global__ __launch_bounds__(256) void k_ma_qkv(
    const float* __restrict__ x,      // [B,S]
    const float* __restrict__ Wq,     // [4,4] row-major: W[e*4+d]
    const float* __restrict__ Wk,
    const float* __restrict__ Wv,
    float4* __restrict__ qws,         // [B*H*S]
    float4* __restrict__ kws,
    float4* __restrict__ vws,
    float4* __restrict__ mmws)        // [B*S*2]  (mm as 2x float4 per pos)
{
    __shared__ float xs[272];
    const int tile = blockIdx.x % (SS / 256);
    const int b    = blockIdx.x / (SS / 256);
    const int s0   = tile * 256;
    const float* xrow = x + b * SS;

    for (int i = threadIdx.x; i < 272; i += 256) {
        int idx = s0 - 8 + i;
        idx = min(max(idx, 0), SS - 1);
        xs[i] = xrow[idx];
    }
    __syncthreads();

    const int t = threadIdx.x;
    const int s = s0 + t;

    float mmv[8];
    float c = xs[8 + t];
    #pragma unroll
    for (int h = 1; h <= 8; ++h) {
        c += xs[8 + t - h] + xs[8 + t + h];
        mmv[h - 1] = c * (1.0f / (float)(2 * h + 1));
    }

    // store mm [B,S,8] as two float4
    mmws[(b * SS + s) * 2 + 0] = make_float4(mmv[0], mmv[1], mmv[2], mmv[3]);
    mmws[(b * SS + s) * 2 + 1] = make_float4(mmv[4], mmv[5], mmv[6], mmv[7]);

    #pragma unroll
    for (int h = 0; h < SH; ++h) {
        const float t0 = mmv[h * 4 + 0];
        const float t1 = mmv[h * 4 + 1];
        const float t2 = mmv[h * 4 + 2];
        const float t3 = mmv[h * 4 + 3];
        float q[4], k[4], v[4];
        #pragma unroll
        for (int e = 0; e < 4; ++e) {
            q[e] = (t0 * Wq[e * 4 + 0] + t1 * Wq[e * 4 + 1] +
                    t2 * Wq[e * 4 + 2] + t3 * Wq[e * 4 + 3]) * 0.5f; // fold 1/sqrt(D)
            k[e] =  t0 * Wk[e * 4 + 0] + t1 * Wk[e * 4 + 1] +
                    t2 * Wk[e * 4 + 2] + t3 * Wk[e * 4 + 3];
            v[e] =  t0 * Wv[e * 4 + 0] + t1 * Wv[e * 4 + 1] +
                    t2 * Wv[e * 4 + 2] + t3 * Wv[e * 4 + 3];
        }
        const int idx = (b * SH + h) * SS + s;
        qws[idx] = make_float4(q[0], q[1], q[2], q[3]);
        kws[idx] = make_float4(k[0], k[1], k[2], k[3]);
        vws[idx] = make_float4(v[0], v[1], v[2], v[3]);
    }
}

// ---------------------------------------------------------------------------
// Kernel 2: attention. One block = (b,h, 256-row q tile). Full K and V for
// the (b,h) in LDS (64 KB). Each thread owns one q row; two-pass softmax.
// All lanes read the same K[j]/V[j] -> LDS broadcast, conflict-free.
// ---------------------------------------------------------------------------
__global__ __launch_bounds__(256) void k_attn(
    const float4* __restrict__ qws,
    const float4* __restrict__ kws,
    const float4* __restrict__ vws,
    float4* __restrict__ ows)
{
    __shared__ float4 KV[2 * SS];   // K then V, 65536 bytes
    const int tile = blockIdx.x % (SS / 256);
    const int bh   = blockIdx.x / (SS / 256);

    const float4* Kg = kws + bh * SS;
    const float4* Vg = vws + bh * SS;
    for (int i = threadIdx.x; i < SS; i += 256) {
        KV[i]      = Kg[i];
        KV[SS + i] = Vg[i];
    }
    __syncthreads();

    const int qrow = tile * 256 + threadIdx.x;
    const float4 q = qws[bh * SS + qrow];

    // pass 1: row max
    float m = -1e30f;
    #pragma unroll 8
    for (int j = 0; j < SS; ++j) {
        const float4 k = KV[j];
        const float sc = q.x * k.x + q.y * k.y + q.z * k.z + q.w * k.w;
        m = fmaxf(m, sc);
    }

    // pass 2: exp-sum + PV accumulate
    float l = 0.0f, ax = 0.0f, ay = 0.0f, az = 0.0f, aw = 0.0f;
    #pragma unroll 4
    for (int j = 0; j < SS; ++j) {
        const float4 k = KV[j];
        const float sc = q.x * k.x + q.y * k.y + q.z * k.z + q.w * k.w;
        const float p = __expf(sc - m);
        l += p;
        const float4 v = KV[SS + j];
        ax += p * v.x; ay += p * v.y; az += p * v.z; aw += p * v.w;
    }
    const float inv = 1.0f / l;
    ows[bh * SS + qrow] = make_float4(ax * inv, ay * inv, az * inv, aw * inv);
}

// ---------------------------------------------------------------------------
// Kernel 3: epilogue. o @ Wo^T + bo, softmax over 8 channels, trend =
// sum(mm * weights), seasonal = x - trend. One thread per position.
// ---------------------------------------------------------------------------
__global__ __launch_bounds__(256) void k_epilogue(
    const float* __restrict__ x,      // [B,S]
    const float* __restrict__ Wo,     // [8,8] row-major W[e*8+f]
    const float* __restrict__ bo,     // [8]
    const float4* __restrict__ ows,   // [B,H,S]
    const float4* __restrict__ mmws,  // [B*S*2]
    float* __restrict__ out)          // seasonal [B*S] then trend [B*S]
{
    const int pos = blockIdx.x * 256 + threadIdx.x;  // = b*S + s
    const int b = pos / SS;
    const int s = pos % SS;

    const float4 o0 = ows[(b * SH + 0) * SS + s];
    const float4 o1 = ows[(b * SH + 1) * SS + s];
    const float ov[8] = {o0.x, o0.y, o0.z, o0.w, o1.x, o1.y, o1.z, o1.w};

    float g[8];
    float m = -1e30f;
    #pragma unroll
    for (int e = 0; e < 8; ++e) {
        float acc = bo[e];
        #pragma unroll
        for (int f = 0; f < 8; ++f) acc += ov[f] * Wo[e * 8 + f];
        g[e] = acc;
        m = fmaxf(m, acc);
    }
    float l = 0.0f;
    #pragma unroll
    for (int e = 0; e < 8; ++e) { g[e] = __expf(g[e] - m); l += g[e]; }
    const float inv = 1.0f / l;

    const float4 mm0 = mmws[pos * 2 + 0];
    const float4 mm1 = mmws[pos * 2 + 1];
    const float mv[8] = {mm0.x, mm0.y, mm0.z, mm0.w, mm1.x, mm1.y, mm1.z, mm1.w};

    float trend = 0.0f;
    #pragma unroll
    for (int e = 0; e < 8; ++e) trend += g[e] * inv * mv[e];

    out[pos]           = x[pos] - trend;   // seasonal
    out[SB * SS + pos] = trend;            // trend
}

extern "C" void kernel_launch(void* const* d_in, const int* in_sizes, int n_in,
                              void* d_out, int out_size, void* d_ws, size_t ws_size,
                              hipStream_t stream) {
    const float* x  = (const float*)d_in[0];
    const float* Wq = (const float*)d_in[1];
    const float* Wk = (const float*)d_in[2];
    const float* Wv = (const float*)d_in[3];
    const float* Wo = (const float*)d_in[4];
    const float* bo = (const float*)d_in[5];

    float4* qws  = (float4*)d_ws;              // B*H*S float4      = 2 MB
    float4* kws  = qws + SB * SH * SS;         // 2 MB
    float4* vws  = kws + SB * SH * SS;         // 2 MB
    float4* mmws = vws + SB * SH * SS;         // B*S*2 float4      = 2 MB
    float4* ows  = mmws + SB * SS * 2;         // B*H*S float4      = 2 MB

    k_ma_qkv<<<SB * (SS / 256), 256, 0, stream>>>(x, Wq, Wk, Wv, qws, kws, vws, mmws);
    k_attn<<<SB * SH * (SS / 256), 256, 0, stream>>>(qws, kws, vws, ows);
    k_epilogue<<<(SB * SS) / 256, 256, 0, stream>>>(x, Wo, bo, ows, mmws, (float*)d_out);
}

// Round 2
// 166.978 us; speedup vs baseline: 1.5195x; 1.5195x over previous
//
#include <hip/hip_runtime.h>

#define SB 32      // batch
#define SS 2048    // sequence
#define SH 2       // heads
#define SD 4       // head dim
#define SE 8       // embed

#define KCHUNKS 4
#define CHK (SS / KCHUNKS)    // 512 keys per block
#define QTILES 2
#define QROWS (SS / QTILES)   // 1024 q rows per block (R=4 per thread)

// ---------------------------------------------------------------------------
// Kernel 1: moving averages (8 odd kernel sizes, replicate pad == clamped
// symmetric window) + QKV projection (4x4 per head, scale 1/sqrt(D) folded
// into q). One block = 256 consecutive positions of one batch row.
// ---------------------------------------------------------------------------
__global__ __launch_bounds__(256) void k_ma_qkv(
    const float* __restrict__ x,      // [B,S]
    const float* __restrict__ Wq,     // [4,4] row-major: W[e*4+d]
    const float* __restrict__ Wk,
    const float* __restrict__ Wv,
    float4* __restrict__ qws,         // [B*H*S]
    float4* __restrict__ kws,
    float4* __restrict__ vws,
    float4* __restrict__ mmws)        // [B*S*2]
{
    __shared__ float xs[272];
    const int tile = blockIdx.x % (SS / 256);
    const int b    = blockIdx.x / (SS / 256);
    const int s0   = tile * 256;
    const float* xrow = x + b * SS;

    for (int i = threadIdx.x; i < 272; i += 256) {
        int idx = s0 - 8 + i;
        idx = min(max(idx, 0), SS - 1);
        xs[i] = xrow[idx];
    }
    __syncthreads();

    const int t = threadIdx.x;
    const int s = s0 + t;

    float mmv[8];
    float c = xs[8 + t];
    #pragma unroll
    for (int h = 1; h <= 8; ++h) {
        c += xs[8 + t - h] + xs[8 + t + h];
        mmv[h - 1] = c * (1.0f / (float)(2 * h + 1));
    }

    mmws[(b * SS + s) * 2 + 0] = make_float4(mmv[0], mmv[1], mmv[2], mmv[3]);
    mmws[(b * SS + s) * 2 + 1] = make_float4(mmv[4], mmv[5], mmv[6], mmv[7]);

    #pragma unroll
    for (int h = 0; h < SH; ++h) {
        const float t0 = mmv[h * 4 + 0];
        const float t1 = mmv[h * 4 + 1];
        const float t2 = mmv[h * 4 + 2];
        const float t3 = mmv[h * 4 + 3];
        float q[4], k[4], v[4];
        #pragma unroll
        for (int e = 0; e < 4; ++e) {
            q[e] = (t0 * Wq[e * 4 + 0] + t1 * Wq[e * 4 + 1] +
                    t2 * Wq[e * 4 + 2] + t3 * Wq[e * 4 + 3]) * 0.5f; // fold 1/sqrt(D)
            k[e] =  t0 * Wk[e * 4 + 0] + t1 * Wk[e * 4 + 1] +
                    t2 * Wk[e * 4 + 2] + t3 * Wk[e * 4 + 3];
            v[e] =  t0 * Wv[e * 4 + 0] + t1 * Wv[e * 4 + 1] +
                    t2 * Wv[e * 4 + 2] + t3 * Wv[e * 4 + 3];
        }
        const int idx = (b * SH + h) * SS + s;
        qws[idx] = make_float4(q[0], q[1], q[2], q[3]);
        kws[idx] = make_float4(k[0], k[1], k[2], k[3]);
        vws[idx] = make_float4(v[0], v[1], v[2], v[3]);
    }
}

// ---------------------------------------------------------------------------
// Kernel 2: attention, register-blocked R=4 q-rows/thread, K split 4-ways.
// Block = (b,h, q-tile of 1024 rows, k-chunk of 512 keys). LDS = 16 KB.
// Writes unnormalized partials (m, l, acc) per q-row per chunk.
// ---------------------------------------------------------------------------
__global__ __launch_bounds__(256) void k_attn(
    const float4* __restrict__ qws,
    const float4* __restrict__ kws,
    const float4* __restrict__ vws,
    float2* __restrict__ pml,    // [KCHUNKS * B*H*S]
    float4* __restrict__ pacc)   // [KCHUNKS * B*H*S]
{
    __shared__ float4 Ksh[CHK];
    __shared__ float4 Vsh[CHK];

    int tmp = blockIdx.x;
    const int kc = tmp % KCHUNKS; tmp /= KCHUNKS;
    const int qt = tmp % QTILES;  tmp /= QTILES;
    const int bh = tmp;

    const float4* Kg = kws + bh * SS + kc * CHK;
    const float4* Vg = vws + bh * SS + kc * CHK;
    for (int i = threadIdx.x; i < CHK; i += 256) {
        Ksh[i] = Kg[i];
        Vsh[i] = Vg[i];
    }
    __syncthreads();

    const int t = threadIdx.x;
    float4 q[4];
    int row[4];
    #pragma unroll
    for (int i = 0; i < 4; ++i) {
        row[i] = qt * QROWS + i * 256 + t;
        q[i] = qws[bh * SS + row[i]];
    }

    // pass 1: row max over this chunk
    float m[4] = {-1e30f, -1e30f, -1e30f, -1e30f};
    #pragma unroll 8
    for (int j = 0; j < CHK; ++j) {
        const float4 k = Ksh[j];
        #pragma unroll
        for (int i = 0; i < 4; ++i) {
            const float sc = q[i].x * k.x + q[i].y * k.y + q[i].z * k.z + q[i].w * k.w;
            m[i] = fmaxf(m[i], sc);
        }
    }

    // pass 2: exp-sum + PV accumulate
    float l[4] = {0.f, 0.f, 0.f, 0.f};
    float4 acc[4];
    #pragma unroll
    for (int i = 0; i < 4; ++i) acc[i] = make_float4(0.f, 0.f, 0.f, 0.f);

    #pragma unroll 4
    for (int j = 0; j < CHK; ++j) {
        const float4 k = Ksh[j];
        const float4 v = Vsh[j];
        #pragma unroll
        for (int i = 0; i < 4; ++i) {
            const float sc = q[i].x * k.x + q[i].y * k.y + q[i].z * k.z + q[i].w * k.w;
            const float p = __expf(sc - m[i]);
            l[i] += p;
            acc[i].x += p * v.x;
            acc[i].y += p * v.y;
            acc[i].z += p * v.z;
            acc[i].w += p * v.w;
        }
    }

    #pragma unroll
    for (int i = 0; i < 4; ++i) {
        const int idx = (kc * SB * SH + bh) * SS + row[i];
        pml[idx]  = make_float2(m[i], l[i]);
        pacc[idx] = acc[i];
    }
}

// ---------------------------------------------------------------------------
// Kernel 3: epilogue. Merge k-chunk partials (flash combine), then
// o @ Wo^T + bo, softmax over 8 channels, trend, seasonal.
// ---------------------------------------------------------------------------
__global__ __launch_bounds__(256) void k_epilogue(
    const float* __restrict__ x,      // [B,S]
    const float* __restrict__ Wo,     // [8,8]
    const float* __restrict__ bo,     // [8]
    const float2* __restrict__ pml,
    const float4* __restrict__ pacc,
    const float4* __restrict__ mmws,
    float* __restrict__ out)          // seasonal [B*S] then trend [B*S]
{
    const int pos = blockIdx.x * 256 + threadIdx.x;  // = b*S + s
    const int b = pos / SS;
    const int s = pos % SS;

    float ov[8];
    #pragma unroll
    for (int h = 0; h < SH; ++h) {
        const int bh = b * SH + h;
        float mstar = -1e30f;
        float2 ml[KCHUNKS];
        float4 pa[KCHUNKS];
        #pragma unroll
        for (int kc = 0; kc < KCHUNKS; ++kc) {
            const int idx = (kc * SB * SH + bh) * SS + s;
            ml[kc] = pml[idx];
            pa[kc] = pacc[idx];
            mstar = fmaxf(mstar, ml[kc].x);
        }
        float lsum = 0.f, ax = 0.f, ay = 0.f, az = 0.f, aw = 0.f;
        #pragma unroll
        for (int kc = 0; kc < KCHUNKS; ++kc) {
            const float w = __expf(ml[kc].x - mstar);
            lsum += ml[kc].y * w;
            ax += pa[kc].x * w;
            ay += pa[kc].y * w;
            az += pa[kc].z * w;
            aw += pa[kc].w * w;
        }
        const float inv = 1.0f / lsum;
        ov[h * 4 + 0] = ax * inv;
        ov[h * 4 + 1] = ay * inv;
        ov[h * 4 + 2] = az * inv;
        ov[h * 4 + 3] = aw * inv;
    }

    float g[8];
    float m = -1e30f;
    #pragma unroll
    for (int e = 0; e < 8; ++e) {
        float acc = bo[e];
        #pragma unroll
        for (int f = 0; f < 8; ++f) acc += ov[f] * Wo[e * 8 + f];
        g[e] = acc;
        m = fmaxf(m, acc);
    }
    float l = 0.0f;
    #pragma unroll
    for (int e = 0; e < 8; ++e) { g[e] = __expf(g[e] - m); l += g[e]; }
    const float inv = 1.0f / l;

    const float4 mm0 = mmws[pos * 2 + 0];
    const float4 mm1 = mmws[pos * 2 + 1];
    const float mv[8] = {mm0.x, mm0.y, mm0.z, mm0.w, mm1.x, mm1.y, mm1.z, mm1.w};

    float trend = 0.0f;
    #pragma unroll
    for (int e = 0; e < 8; ++e) trend += g[e] * inv * mv[e];

    out[pos]           = x[pos] - trend;   // seasonal
    out[SB * SS + pos] = trend;            // trend
}

extern "C" void kernel_launch(void* const* d_in, const int* in_sizes, int n_in,
                              void* d_out, int out_size, void* d_ws, size_t ws_size,
                              hipStream_t stream) {
    const float* x  = (const float*)d_in[0];
    const float* Wq = (const float*)d_in[1];
    const float* Wk = (const float*)d_in[2];
    const float* Wv = (const float*)d_in[3];
    const float* Wo = (const float*)d_in[4];
    const float* bo = (const float*)d_in[5];

    float4* qws  = (float4*)d_ws;              // B*H*S float4 = 2 MB
    float4* kws  = qws + SB * SH * SS;         // 2 MB
    float4* vws  = kws + SB * SH * SS;         // 2 MB
    float4* mmws = vws + SB * SH * SS;         // 2 MB
    float4* pacc = mmws + SB * SS * 2;         // KCHUNKS*B*H*S float4 = 8 MB
    float2* pml  = (float2*)(pacc + KCHUNKS * SB * SH * SS); // 4 MB

    k_ma_qkv<<<SB * (SS / 256), 256, 0, stream>>>(x, Wq, Wk, Wv, qws, kws, vws, mmws);
    k_attn<<<SB * SH * QTILES * KCHUNKS, 256, 0, stream>>>(qws, kws, vws, pml, pacc);
    k_epilogue<<<(SB * SS) / 256, 256, 0, stream>>>(x, Wo, bo, pml, pacc, mmws, (float*)d_out);
}

// Round 4
// 134.339 us; speedup vs baseline: 1.8887x; 1.2430x over previous
//
#include <hip/hip_runtime.h>

#define SB 32      // batch
#define SS 2048    // sequence
#define SH 2       // heads
#define SD 4       // head dim
#define SE 8       // embed

#define KCHUNKS 8
#define CHK (SS / KCHUNKS)    // 256 keys per block
#define QTILES 2
#define QROWS (SS / QTILES)   // 1024 q rows per block (R=4 per thread)

#define LOG2E 1.44269504f

// ---------------------------------------------------------------------------
// Kernel 1: moving averages (8 odd kernel sizes, replicate pad == clamped
// symmetric window) + QKV projection (4x4 per head, scale 1/sqrt(D) folded
// into q). One block = 256 consecutive positions of one batch row.
// ---------------------------------------------------------------------------
__global__ __launch_bounds__(256) void k_ma_qkv(
    const float* __restrict__ x,      // [B,S]
    const float* __restrict__ Wq,     // [4,4] row-major: W[e*4+d]
    const float* __restrict__ Wk,
    const float* __restrict__ Wv,
    float4* __restrict__ qws,         // [B*H*S]
    float4* __restrict__ kws,
    float4* __restrict__ vws,
    float4* __restrict__ mmws)        // [B*S*2]
{
    __shared__ float xs[272];
    const int tile = blockIdx.x % (SS / 256);
    const int b    = blockIdx.x / (SS / 256);
    const int s0   = tile * 256;
    const float* xrow = x + b * SS;

    for (int i = threadIdx.x; i < 272; i += 256) {
        int idx = s0 - 8 + i;
        idx = min(max(idx, 0), SS - 1);
        xs[i] = xrow[idx];
    }
    __syncthreads();

    const int t = threadIdx.x;
    const int s = s0 + t;

    float mmv[8];
    float c = xs[8 + t];
    #pragma unroll
    for (int h = 1; h <= 8; ++h) {
        c += xs[8 + t - h] + xs[8 + t + h];
        mmv[h - 1] = c * (1.0f / (float)(2 * h + 1));
    }

    mmws[(b * SS + s) * 2 + 0] = make_float4(mmv[0], mmv[1], mmv[2], mmv[3]);
    mmws[(b * SS + s) * 2 + 1] = make_float4(mmv[4], mmv[5], mmv[6], mmv[7]);

    #pragma unroll
    for (int h = 0; h < SH; ++h) {
        const float t0 = mmv[h * 4 + 0];
        const float t1 = mmv[h * 4 + 1];
        const float t2 = mmv[h * 4 + 2];
        const float t3 = mmv[h * 4 + 3];
        float q[4], k[4], v[4];
        #pragma unroll
        for (int e = 0; e < 4; ++e) {
            q[e] = (t0 * Wq[e * 4 + 0] + t1 * Wq[e * 4 + 1] +
                    t2 * Wq[e * 4 + 2] + t3 * Wq[e * 4 + 3]) * 0.5f; // fold 1/sqrt(D)
            k[e] =  t0 * Wk[e * 4 + 0] + t1 * Wk[e * 4 + 1] +
                    t2 * Wk[e * 4 + 2] + t3 * Wk[e * 4 + 3];
            v[e] =  t0 * Wv[e * 4 + 0] + t1 * Wv[e * 4 + 1] +
                    t2 * Wv[e * 4 + 2] + t3 * Wv[e * 4 + 3];
        }
        const int idx = (b * SH + h) * SS + s;
        qws[idx] = make_float4(q[0], q[1], q[2], q[3]);
        kws[idx] = make_float4(k[0], k[1], k[2], k[3]);
        vws[idx] = make_float4(v[0], v[1], v[2], v[3]);
    }
}

// ---------------------------------------------------------------------------
// Kernel 2: attention, single pass. R=4 q-rows/thread, K split 8 ways.
// No max pass: m[i] = |q[i]| * max_j |k_j| (Cauchy-Schwarz upper bound,
// computed once per block) guarantees exp args <= 0; softmax is
// shift-invariant so the result is exact. Underflow impossible here
// (score magnitudes are small; slack << 80).
// Block = (b,h, q-tile of 1024 rows, k-chunk of 256 keys). LDS = 8 KB + red.
// ---------------------------------------------------------------------------
__global__ __launch_bounds__(256) void k_attn(
    const float4* __restrict__ qws,
    const float4* __restrict__ kws,
    const float4* __restrict__ vws,
    float2* __restrict__ pml,    // [KCHUNKS * B*H*S]  (m, l)
    float4* __restrict__ pacc)   // [KCHUNKS * B*H*S]
{
    __shared__ float4 Ksh[CHK];
    __shared__ float4 Vsh[CHK];
    __shared__ float  red[256];

    int tmp = blockIdx.x;
    const int kc = tmp % KCHUNKS; tmp /= KCHUNKS;
    const int qt = tmp % QTILES;  tmp /= QTILES;
    const int bh = tmp;

    const int t = threadIdx.x;

    // stage K,V chunk; each thread loads exactly one key (CHK == 256)
    const float4 kv_k = kws[bh * SS + kc * CHK + t];
    const float4 kv_v = vws[bh * SS + kc * CHK + t];
    Ksh[t] = kv_k;
    Vsh[t] = kv_v;
    // block max of |k|^2
    red[t] = kv_k.x * kv_k.x + kv_k.y * kv_k.y + kv_k.z * kv_k.z + kv_k.w * kv_k.w;
    __syncthreads();
    #pragma unroll
    for (int sft = 128; sft > 0; sft >>= 1) {
        if (t < sft) red[t] = fmaxf(red[t], red[t + sft]);
        __syncthreads();
    }
    const float kk_max = red[0];

    float4 q[4];
    float  mq[4];   // -m * log2e
    float  mval[4]; // m
    int row[4];
    #pragma unroll
    for (int i = 0; i < 4; ++i) {
        row[i] = qt * QROWS + i * 256 + t;
        q[i] = qws[bh * SS + row[i]];
        const float q2 = q[i].x * q[i].x + q[i].y * q[i].y +
                         q[i].z * q[i].z + q[i].w * q[i].w;
        const float m = sqrtf(q2 * kk_max);
        mval[i] = m;
        mq[i] = -m * LOG2E;
    }

    float l[4] = {0.f, 0.f, 0.f, 0.f};
    float4 acc[4];
    #pragma unroll
    for (int i = 0; i < 4; ++i) acc[i] = make_float4(0.f, 0.f, 0.f, 0.f);

    #pragma unroll 8
    for (int j = 0; j < CHK; ++j) {
        const float4 k = Ksh[j];
        const float4 v = Vsh[j];
        #pragma unroll
        for (int i = 0; i < 4; ++i) {
            const float sc = q[i].x * k.x + q[i].y * k.y + q[i].z * k.z + q[i].w * k.w;
            const float p = exp2f(fmaf(sc, LOG2E, mq[i]));
            l[i] += p;
            acc[i].x += p * v.x;
            acc[i].y += p * v.y;
            acc[i].z += p * v.z;
            acc[i].w += p * v.w;
        }
    }

    #pragma unroll
    for (int i = 0; i < 4; ++i) {
        const int idx = (kc * SB * SH + bh) * SS + row[i];
        pml[idx]  = make_float2(mval[i], l[i]);
        pacc[idx] = acc[i];
    }
}

// ---------------------------------------------------------------------------
// Kernel 3: epilogue. Merge k-chunk partials (flash combine), then
// o @ Wo^T + bo, softmax over 8 channels, trend, seasonal.
// ---------------------------------------------------------------------------
__global__ __launch_bounds__(256) void k_epilogue(
    const float* __restrict__ x,      // [B,S]
    const float* __restrict__ Wo,     // [8,8]
    const float* __restrict__ bo,     // [8]
    const float2* __restrict__ pml,
    const float4* __restrict__ pacc,
    const float4* __restrict__ mmws,
    float* __restrict__ out)          // seasonal [B*S] then trend [B*S]
{
    const int pos = blockIdx.x * 256 + threadIdx.x;  // = b*S + s
    const int b = pos / SS;
    const int s = pos % SS;

    float ov[8];
    #pragma unroll
    for (int h = 0; h < SH; ++h) {
        const int bh = b * SH + h;
        float mstar = -1e30f;
        float2 ml[KCHUNKS];
        float4 pa[KCHUNKS];
        #pragma unroll
        for (int kc = 0; kc < KCHUNKS; ++kc) {
            const int idx = (kc * SB * SH + bh) * SS + s;
            ml[kc] = pml[idx];
            pa[kc] = pacc[idx];
            mstar = fmaxf(mstar, ml[kc].x);
        }
        float lsum = 0.f, ax = 0.f, ay = 0.f, az = 0.f, aw = 0.f;
        #pragma unroll
        for (int kc = 0; kc < KCHUNKS; ++kc) {
            const float w = __expf(ml[kc].x - mstar);
            lsum += ml[kc].y * w;
            ax += pa[kc].x * w;
            ay += pa[kc].y * w;
            az += pa[kc].z * w;
            aw += pa[kc].w * w;
        }
        const float inv = 1.0f / lsum;
        ov[h * 4 + 0] = ax * inv;
        ov[h * 4 + 1] = ay * inv;
        ov[h * 4 + 2] = az * inv;
        ov[h * 4 + 3] = aw * inv;
    }

    float g[8];
    float m = -1e30f;
    #pragma unroll
    for (int e = 0; e < 8; ++e) {
        float acc = bo[e];
        #pragma unroll
        for (int f = 0; f < 8; ++f) acc += ov[f] * Wo[e * 8 + f];
        g[e] = acc;
        m = fmaxf(m, acc);
    }
    float l = 0.0f;
    #pragma unroll
    for (int e = 0; e < 8; ++e) { g[e] = __expf(g[e] - m); l += g[e]; }
    const float inv = 1.0f / l;

    const float4 mm0 = mmws[pos * 2 + 0];
    const float4 mm1 = mmws[pos * 2 + 1];
    const float mv[8] = {mm0.x, mm0.y, mm0.z, mm0.w, mm1.x, mm1.y, mm1.z, mm1.w};

    float trend = 0.0f;
    #pragma unroll
    for (int e = 0; e < 8; ++e) trend += g[e] * inv * mv[e];

    out[pos]           = x[pos] - trend;   // seasonal
    out[SB * SS + pos] = trend;            // trend
}

extern "C" void kernel_launch(void* const* d_in, const int* in_sizes, int n_in,
                              void* d_out, int out_size, void* d_ws, size_t ws_size,
                              hipStream_t stream) {
    const float* x  = (const float*)d_in[0];
    const float* Wq = (const float*)d_in[1];
    const float* Wk = (const float*)d_in[2];
    const float* Wv = (const float*)d_in[3];
    const float* Wo = (const float*)d_in[4];
    const float* bo = (const float*)d_in[5];

    float4* qws  = (float4*)d_ws;              // B*H*S float4 = 2 MB
    float4* kws  = qws + SB * SH * SS;         // 2 MB
    float4* vws  = kws + SB * SH * SS;         // 2 MB
    float4* mmws = vws + SB * SH * SS;         // 2 MB
    float4* pacc = mmws + SB * SS * 2;         // KCHUNKS*B*H*S float4 = 16 MB
    float2* pml  = (float2*)(pacc + KCHUNKS * SB * SH * SS); // 8 MB

    k_ma_qkv<<<SB * (SS / 256), 256, 0, stream>>>(x, Wq, Wk, Wv, qws, kws, vws, mmws);
    k_attn<<<SB * SH * QTILES * KCHUNKS, 256, 0, stream>>>(qws, kws, vws, pml, pacc);
    k_epilogue<<<(SB * SS) / 256, 256, 0, stream>>>(x, Wo, bo, pml, pacc, mmws, (float*)d_out);
}

// Round 5
// 117.595 us; speedup vs baseline: 2.1577x; 1.1424x over previous
//
#include <hip/hip_runtime.h>

#define SB 32      // batch
#define SS 2048    // sequence
#define SH 2       // heads
#define SD 4       // head dim
#define SE 8       // embed

#define KCHUNKS 8
#define CHK (SS / KCHUNKS)    // 256 keys per chunk
#define QTILES 4
#define QROWS (SS / QTILES)   // 512 q rows per block (R=2 per thread)
#define RROWS 2

#define LOG2E 1.44269504f

// ---------------------------------------------------------------------------
// Kernel 1: moving averages (8 odd kernel sizes, replicate pad == clamped
// symmetric window) + QKV projection (4x4 per head). Scale 1/sqrt(D) AND
// log2(e) folded into q, so attention scores are already in log2 units.
// ---------------------------------------------------------------------------
__global__ __launch_bounds__(256) void k_ma_qkv(
    const float* __restrict__ x,      // [B,S]
    const float* __restrict__ Wq,     // [4,4] row-major: W[e*4+d]
    const float* __restrict__ Wk,
    const float* __restrict__ Wv,
    float4* __restrict__ qws,         // [B*H*S]
    float4* __restrict__ kws,
    float4* __restrict__ vws,
    float4* __restrict__ mmws)        // [B*S*2]
{
    __shared__ float xs[272];
    const int tile = blockIdx.x % (SS / 256);
    const int b    = blockIdx.x / (SS / 256);
    const int s0   = tile * 256;
    const float* xrow = x + b * SS;

    for (int i = threadIdx.x; i < 272; i += 256) {
        int idx = s0 - 8 + i;
        idx = min(max(idx, 0), SS - 1);
        xs[i] = xrow[idx];
    }
    __syncthreads();

    const int t = threadIdx.x;
    const int s = s0 + t;

    float mmv[8];
    float c = xs[8 + t];
    #pragma unroll
    for (int h = 1; h <= 8; ++h) {
        c += xs[8 + t - h] + xs[8 + t + h];
        mmv[h - 1] = c * (1.0f / (float)(2 * h + 1));
    }

    mmws[(b * SS + s) * 2 + 0] = make_float4(mmv[0], mmv[1], mmv[2], mmv[3]);
    mmws[(b * SS + s) * 2 + 1] = make_float4(mmv[4], mmv[5], mmv[6], mmv[7]);

    const float qscale = 0.5f * LOG2E;  // 1/sqrt(D) * log2(e)
    #pragma unroll
    for (int h = 0; h < SH; ++h) {
        const float t0 = mmv[h * 4 + 0];
        const float t1 = mmv[h * 4 + 1];
        const float t2 = mmv[h * 4 + 2];
        const float t3 = mmv[h * 4 + 3];
        float q[4], k[4], v[4];
        #pragma unroll
        for (int e = 0; e < 4; ++e) {
            q[e] = (t0 * Wq[e * 4 + 0] + t1 * Wq[e * 4 + 1] +
                    t2 * Wq[e * 4 + 2] + t3 * Wq[e * 4 + 3]) * qscale;
            k[e] =  t0 * Wk[e * 4 + 0] + t1 * Wk[e * 4 + 1] +
                    t2 * Wk[e * 4 + 2] + t3 * Wk[e * 4 + 3];
            v[e] =  t0 * Wv[e * 4 + 0] + t1 * Wv[e * 4 + 1] +
                    t2 * Wv[e * 4 + 2] + t3 * Wv[e * 4 + 3];
        }
        const int idx = (b * SH + h) * SS + s;
        qws[idx] = make_float4(q[0], q[1], q[2], q[3]);
        kws[idx] = make_float4(k[0], k[1], k[2], k[3]);
        vws[idx] = make_float4(v[0], v[1], v[2], v[3]);
    }
}

// ---------------------------------------------------------------------------
// Kernel 2: attention, single pass, NO K/V LDS staging. The k-chunk (8 KB K
// + 8 KB V) is L1-resident and the loop index j is wave-uniform, so Kg[j]
// compiles to scalar/broadcast loads — LDS pipe and per-lane VMEM freed.
// R=2 q-rows/thread; m = |q|*max|k| chunk bound (Cauchy-Schwarz), folded
// into the dot-product seed; all exponentials in base 2.
// Grid = B*H * QTILES * KCHUNKS = 2048 blocks -> 8 blocks/CU, 32 waves/CU.
// ---------------------------------------------------------------------------
__global__ __launch_bounds__(256) void k_attn(
    const float4* __restrict__ qws,
    const float4* __restrict__ kws,
    const float4* __restrict__ vws,
    float2* __restrict__ pml,    // [KCHUNKS * B*H*S]  (m_log2, l)
    float4* __restrict__ pacc)   // [KCHUNKS * B*H*S]
{
    __shared__ float red[256];

    int tmp = blockIdx.x;
    const int kc = tmp % KCHUNKS; tmp /= KCHUNKS;
    const int qt = tmp % QTILES;  tmp /= QTILES;
    const int bh = tmp;

    const int t = threadIdx.x;

    const float4* __restrict__ Kg = kws + bh * SS + kc * CHK;
    const float4* __restrict__ Vg = vws + bh * SS + kc * CHK;

    // block max of |k|^2 over this chunk (CHK == 256: one key per thread)
    {
        const float4 kk = Kg[t];
        red[t] = kk.x * kk.x + kk.y * kk.y + kk.z * kk.z + kk.w * kk.w;
    }
    __syncthreads();
    #pragma unroll
    for (int sft = 128; sft > 0; sft >>= 1) {
        if (t < sft) red[t] = fmaxf(red[t], red[t + sft]);
        __syncthreads();
    }
    const float kk_max = red[0];

    float4 q[RROWS];
    float  mq[RROWS];    // -m (log2 units), seeds the dot product
    float  mval[RROWS];  // m (log2 units)
    int row[RROWS];
    #pragma unroll
    for (int i = 0; i < RROWS; ++i) {
        row[i] = qt * QROWS + i * 256 + t;
        q[i] = qws[bh * SS + row[i]];
        const float q2 = q[i].x * q[i].x + q[i].y * q[i].y +
                         q[i].z * q[i].z + q[i].w * q[i].w;
        const float m = sqrtf(q2 * kk_max);
        mval[i] = m;
        mq[i] = -m;
    }

    float l[RROWS] = {0.f, 0.f};
    float4 acc[RROWS];
    #pragma unroll
    for (int i = 0; i < RROWS; ++i) acc[i] = make_float4(0.f, 0.f, 0.f, 0.f);

    #pragma unroll 8
    for (int j = 0; j < CHK; ++j) {
        const float4 k = Kg[j];   // wave-uniform -> scalar broadcast load
        const float4 v = Vg[j];
        #pragma unroll
        for (int i = 0; i < RROWS; ++i) {
            // dot seeded with -m: arg = q.k - m  (log2 units)
            const float arg = fmaf(q[i].x, k.x,
                              fmaf(q[i].y, k.y,
                              fmaf(q[i].z, k.z,
                              fmaf(q[i].w, k.w, mq[i]))));
            const float p = exp2f(arg);
            l[i] += p;
            acc[i].x += p * v.x;
            acc[i].y += p * v.y;
            acc[i].z += p * v.z;
            acc[i].w += p * v.w;
        }
    }

    #pragma unroll
    for (int i = 0; i < RROWS; ++i) {
        const int idx = (kc * SB * SH + bh) * SS + row[i];
        pml[idx]  = make_float2(mval[i], l[i]);
        pacc[idx] = acc[i];
    }
}

// ---------------------------------------------------------------------------
// Kernel 3: epilogue. Merge k-chunk partials (flash combine, base-2 units),
// then o @ Wo^T + bo, softmax over 8 channels, trend, seasonal.
// ---------------------------------------------------------------------------
__global__ __launch_bounds__(256) void k_epilogue(
    const float* __restrict__ x,      // [B,S]
    const float* __restrict__ Wo,     // [8,8]
    const float* __restrict__ bo,     // [8]
    const float2* __restrict__ pml,
    const float4* __restrict__ pacc,
    const float4* __restrict__ mmws,
    float* __restrict__ out)          // seasonal [B*S] then trend [B*S]
{
    const int pos = blockIdx.x * 256 + threadIdx.x;  // = b*S + s
    const int b = pos / SS;
    const int s = pos % SS;

    float ov[8];
    #pragma unroll
    for (int h = 0; h < SH; ++h) {
        const int bh = b * SH + h;
        float mstar = -1e30f;
        float2 ml[KCHUNKS];
        float4 pa[KCHUNKS];
        #pragma unroll
        for (int kc = 0; kc < KCHUNKS; ++kc) {
            const int idx = (kc * SB * SH + bh) * SS + s;
            ml[kc] = pml[idx];
            pa[kc] = pacc[idx];
            mstar = fmaxf(mstar, ml[kc].x);
        }
        float lsum = 0.f, ax = 0.f, ay = 0.f, az = 0.f, aw = 0.f;
        #pragma unroll
        for (int kc = 0; kc < KCHUNKS; ++kc) {
            const float w = exp2f(ml[kc].x - mstar);  // log2-unit merge
            lsum += ml[kc].y * w;
            ax += pa[kc].x * w;
            ay += pa[kc].y * w;
            az += pa[kc].z * w;
            aw += pa[kc].w * w;
        }
        const float inv = 1.0f / lsum;
        ov[h * 4 + 0] = ax * inv;
        ov[h * 4 + 1] = ay * inv;
        ov[h * 4 + 2] = az * inv;
        ov[h * 4 + 3] = aw * inv;
    }

    float g[8];
    float m = -1e30f;
    #pragma unroll
    for (int e = 0; e < 8; ++e) {
        float acc = bo[e];
        #pragma unroll
        for (int f = 0; f < 8; ++f) acc += ov[f] * Wo[e * 8 + f];
        g[e] = acc;
        m = fmaxf(m, acc);
    }
    float l = 0.0f;
    #pragma unroll
    for (int e = 0; e < 8; ++e) { g[e] = __expf(g[e] - m); l += g[e]; }
    const float inv = 1.0f / l;

    const float4 mm0 = mmws[pos * 2 + 0];
    const float4 mm1 = mmws[pos * 2 + 1];
    const float mv[8] = {mm0.x, mm0.y, mm0.z, mm0.w, mm1.x, mm1.y, mm1.z, mm1.w};

    float trend = 0.0f;
    #pragma unroll
    for (int e = 0; e < 8; ++e) trend += g[e] * inv * mv[e];

    out[pos]           = x[pos] - trend;   // seasonal
    out[SB * SS + pos] = trend;            // trend
}

extern "C" void kernel_launch(void* const* d_in, const int* in_sizes, int n_in,
                              void* d_out, int out_size, void* d_ws, size_t ws_size,
                              hipStream_t stream) {
    const float* x  = (const float*)d_in[0];
    const float* Wq = (const float*)d_in[1];
    const float* Wk = (const float*)d_in[2];
    const float* Wv = (const float*)d_in[3];
    const float* Wo = (const float*)d_in[4];
    const float* bo = (const float*)d_in[5];

    float4* qws  = (float4*)d_ws;              // B*H*S float4 = 2 MB
    float4* kws  = qws + SB * SH * SS;         // 2 MB
    float4* vws  = kws + SB * SH * SS;         // 2 MB
    float4* mmws = vws + SB * SH * SS;         // 2 MB
    float4* pacc = mmws + SB * SS * 2;         // KCHUNKS*B*H*S float4 = 16 MB
    float2* pml  = (float2*)(pacc + KCHUNKS * SB * SH * SS); // 8 MB

    k_ma_qkv<<<SB * (SS / 256), 256, 0, stream>>>(x, Wq, Wk, Wv, qws, kws, vws, mmws);
    k_attn<<<SB * SH * QTILES * KCHUNKS, 256, 0, stream>>>(qws, kws, vws, pml, pacc);
    k_epilogue<<<(SB * SS) / 256, 256, 0, stream>>>(x, Wo, bo, pml, pacc, mmws, (float*)d_out);
}